// Round 15
// baseline (437.646 us; speedup 1.0000x reference)
//
#include <hip/hip_runtime.h>
#include <hip/hip_fp16.h>
#include <math.h>

#define LSEQ   2048
#define DMODEL 512
#define NHEAD  8
#define DK     64
#define UK     38            // u = int(5*ln(2048)) = 38

typedef __attribute__((ext_vector_type(8))) _Float16 v8h;
typedef __attribute__((ext_vector_type(4))) float    v4f;

// order-preserving monotone maps (verified R2/R3)
__device__ __forceinline__ unsigned long long mapu64(double x){
    unsigned long long s = (unsigned long long)__double_as_longlong(x);
    return (s & 0x8000000000000000ull) ? ~s : (s | 0x8000000000000000ull);
}
__device__ __forceinline__ unsigned map32(float x){
    unsigned s = __float_as_uint(x);
    return (s & 0x80000000u) ? ~s : (s | 0x80000000u);
}
__device__ __forceinline__ float unmap32(unsigned u){
    unsigned s = (u & 0x80000000u) ? (u & 0x7fffffffu) : ~u;
    return __uint_as_float(s);
}
// u16 monotone map for raw half bits
__device__ __forceinline__ unsigned map16(unsigned h){
    return (h & 0x8000u) ? ((~h) & 0xFFFFu) : (h | 0x8000u);
}

// ------- fused Q/K (f64, exact) + V (f32) projections, double-buffered ------------
// Register-staged pipeline: issue tile k+1 global loads -> compute tile k ->
// write LDS buffer p^1 -> ONE barrier (was 2/step). Staging values and FMA
// order unchanged -> outputs bit-identical to R14.
__global__ __launch_bounds__(256) void gemm_qkv(
    const float* __restrict__ X, const float* __restrict__ Wq,
    const float* __restrict__ Wk, const float* __restrict__ Wv,
    const float* __restrict__ bq, const float* __restrict__ bk,
    const float* __restrict__ bv,
    double* __restrict__ qD, double* __restrict__ kRow,
    __half* __restrict__ qH, __half* __restrict__ kH, float* __restrict__ vB)
{
    const int mode = blockIdx.z;                 // 0 = Q, 1 = K, 2 = V
    const float* __restrict__ W    = (mode == 0) ? Wq : (mode == 1 ? Wk : Wv);
    const float* __restrict__ bias = (mode == 0) ? bq : (mode == 1 ? bk : bv);
    const int r0 = blockIdx.x * 64, c0 = blockIdx.y * 64;
    __shared__ float Xs[2][32][68];
    __shared__ float Ws[2][32][68];
    const int tid = threadIdx.x;
    const int tx = tid & 15, ty = tid >> 4;
    // this thread's two staging slots (same mapping as R14)
    const int m_0 = tid >> 3,          kg_0 = (tid & 7) << 2;
    const int m_1 = (256 + tid) >> 3,  kg_1 = ((256 + tid) & 7) << 2;

    // prologue: stage kb=0 into buffer 0
    {
        float4 x0 = *(const float4*)&X[(r0 + m_0) * DMODEL + kg_0];
        float4 w0 = *(const float4*)&W[(c0 + m_0) * DMODEL + kg_0];
        float4 x1 = *(const float4*)&X[(r0 + m_1) * DMODEL + kg_1];
        float4 w1 = *(const float4*)&W[(c0 + m_1) * DMODEL + kg_1];
        Xs[0][kg_0+0][m_0] = x0.x; Xs[0][kg_0+1][m_0] = x0.y;
        Xs[0][kg_0+2][m_0] = x0.z; Xs[0][kg_0+3][m_0] = x0.w;
        Ws[0][kg_0+0][m_0] = w0.x; Ws[0][kg_0+1][m_0] = w0.y;
        Ws[0][kg_0+2][m_0] = w0.z; Ws[0][kg_0+3][m_0] = w0.w;
        Xs[0][kg_1+0][m_1] = x1.x; Xs[0][kg_1+1][m_1] = x1.y;
        Xs[0][kg_1+2][m_1] = x1.z; Xs[0][kg_1+3][m_1] = x1.w;
        Ws[0][kg_1+0][m_1] = w1.x; Ws[0][kg_1+1][m_1] = w1.y;
        Ws[0][kg_1+2][m_1] = w1.z; Ws[0][kg_1+3][m_1] = w1.w;
    }
    __syncthreads();

    if (mode < 2){
        double acc[4][4] = {};
        for (int it = 0; it < 16; ++it){
            const int p = it & 1;
            float4 x0, w0, x1, w1;
            const bool more = (it + 1 < 16);
            if (more){
                int kb = (it + 1) << 5;
                x0 = *(const float4*)&X[(r0 + m_0) * DMODEL + kb + kg_0];
                w0 = *(const float4*)&W[(c0 + m_0) * DMODEL + kb + kg_0];
                x1 = *(const float4*)&X[(r0 + m_1) * DMODEL + kb + kg_1];
                w1 = *(const float4*)&W[(c0 + m_1) * DMODEL + kb + kg_1];
            }
            #pragma unroll
            for (int kk = 0; kk < 32; ++kk){
                float4 av = *(const float4*)&Xs[p][kk][ty << 2];
                float4 bvv = *(const float4*)&Ws[p][kk][tx << 2];
                double a[4] = {(double)av.x, (double)av.y, (double)av.z, (double)av.w};
                double b[4] = {(double)bvv.x, (double)bvv.y, (double)bvv.z, (double)bvv.w};
                #pragma unroll
                for (int ii = 0; ii < 4; ++ii)
                    #pragma unroll
                    for (int jj = 0; jj < 4; ++jj)
                        acc[ii][jj] = fma(a[ii], b[jj], acc[ii][jj]);
            }
            if (more){
                const int q = p ^ 1;
                Xs[q][kg_0+0][m_0] = x0.x; Xs[q][kg_0+1][m_0] = x0.y;
                Xs[q][kg_0+2][m_0] = x0.z; Xs[q][kg_0+3][m_0] = x0.w;
                Ws[q][kg_0+0][m_0] = w0.x; Ws[q][kg_0+1][m_0] = w0.y;
                Ws[q][kg_0+2][m_0] = w0.z; Ws[q][kg_0+3][m_0] = w0.w;
                Xs[q][kg_1+0][m_1] = x1.x; Xs[q][kg_1+1][m_1] = x1.y;
                Xs[q][kg_1+2][m_1] = x1.z; Xs[q][kg_1+3][m_1] = x1.w;
                Ws[q][kg_1+0][m_1] = w1.x; Ws[q][kg_1+1][m_1] = w1.y;
                Ws[q][kg_1+2][m_1] = w1.z; Ws[q][kg_1+3][m_1] = w1.w;
            }
            __syncthreads();
        }
        #pragma unroll
        for (int ii = 0; ii < 4; ++ii){
            int r = r0 + (ty << 2) + ii;
            int bidx = r >> 11, l = r & 2047;
            int h = c0 >> 6;
            size_t rowb = (size_t)(bidx * NHEAD + h) * LSEQ + l;
            _Float16 hv[4];
            #pragma unroll
            for (int jj = 0; jj < 4; ++jj){
                int dk = (tx << 2) + jj;
                double v = acc[ii][jj] + (double)bias[c0 + dk];
                if (mode == 0){
                    v *= 0.125;                  // exact pow2 scale
                    qD[rowb * DK + dk] = v;
                } else {
                    kRow[rowb * DK + dk] = v;
                }
                hv[jj] = (_Float16)v;
            }
            if (mode == 0) *(ushort4*)&qH[rowb * DK + (tx << 2)] = *(ushort4*)hv;
            else           *(ushort4*)&kH[rowb * DK + (tx << 2)] = *(ushort4*)hv;
        }
    } else {
        float acc[4][4] = {};
        for (int it = 0; it < 16; ++it){
            const int p = it & 1;
            float4 x0, w0, x1, w1;
            const bool more = (it + 1 < 16);
            if (more){
                int kb = (it + 1) << 5;
                x0 = *(const float4*)&X[(r0 + m_0) * DMODEL + kb + kg_0];
                w0 = *(const float4*)&W[(c0 + m_0) * DMODEL + kb + kg_0];
                x1 = *(const float4*)&X[(r0 + m_1) * DMODEL + kb + kg_1];
                w1 = *(const float4*)&W[(c0 + m_1) * DMODEL + kb + kg_1];
            }
            #pragma unroll
            for (int kk = 0; kk < 32; ++kk){
                float4 av = *(const float4*)&Xs[p][kk][ty << 2];
                float4 bvv = *(const float4*)&Ws[p][kk][tx << 2];
                float a[4] = {av.x, av.y, av.z, av.w};
                float b[4] = {bvv.x, bvv.y, bvv.z, bvv.w};
                #pragma unroll
                for (int ii = 0; ii < 4; ++ii)
                    #pragma unroll
                    for (int jj = 0; jj < 4; ++jj)
                        acc[ii][jj] = fmaf(a[ii], b[jj], acc[ii][jj]);
            }
            if (more){
                const int q = p ^ 1;
                Xs[q][kg_0+0][m_0] = x0.x; Xs[q][kg_0+1][m_0] = x0.y;
                Xs[q][kg_0+2][m_0] = x0.z; Xs[q][kg_0+3][m_0] = x0.w;
                Ws[q][kg_0+0][m_0] = w0.x; Ws[q][kg_0+1][m_0] = w0.y;
                Ws[q][kg_0+2][m_0] = w0.z; Ws[q][kg_0+3][m_0] = w0.w;
                Xs[q][kg_1+0][m_1] = x1.x; Xs[q][kg_1+1][m_1] = x1.y;
                Xs[q][kg_1+2][m_1] = x1.z; Xs[q][kg_1+3][m_1] = x1.w;
                Ws[q][kg_1+0][m_1] = w1.x; Ws[q][kg_1+1][m_1] = w1.y;
                Ws[q][kg_1+2][m_1] = w1.z; Ws[q][kg_1+3][m_1] = w1.w;
            }
            __syncthreads();
        }
        #pragma unroll
        for (int ii = 0; ii < 4; ++ii){
            int r = r0 + (ty << 2) + ii;
            float4 o;
            o.x = acc[ii][0] + bias[c0 + (tx << 2) + 0];
            o.y = acc[ii][1] + bias[c0 + (tx << 2) + 1];
            o.z = acc[ii][2] + bias[c0 + (tx << 2) + 2];
            o.w = acc[ii][3] + bias[c0 + (tx << 2) + 3];
            int bidx = r >> 11, l = r & 2047, h = c0 >> 6;
            *(float4*)&vB[((size_t)(bidx * NHEAD + h) * LSEQ + l) * DK + (tx << 2)] = o;
        }
    }
}

// ---------------- f32 GEMM: O projection ------------------------------------------
__global__ __launch_bounds__(256) void gemm_f32(
    const float* __restrict__ X, const float* __restrict__ W,
    const float* __restrict__ bias, float* __restrict__ out)
{
    const int r0 = blockIdx.x * 64, c0 = blockIdx.y * 64;
    __shared__ float Xs[32][68];
    __shared__ float Ws[32][68];
    const int tid = threadIdx.x;
    const int tx = tid & 15, ty = tid >> 4;
    float acc[4][4] = {};
    for (int kb = 0; kb < DMODEL; kb += 32){
        __syncthreads();
        #pragma unroll
        for (int i = 0; i < 2; ++i){
            int f4 = i * 256 + tid;
            int m = f4 >> 3, kg = (f4 & 7) << 2;
            float4 xv = *(const float4*)&X[(r0 + m) * DMODEL + kb + kg];
            Xs[kg+0][m] = xv.x; Xs[kg+1][m] = xv.y; Xs[kg+2][m] = xv.z; Xs[kg+3][m] = xv.w;
            float4 wv = *(const float4*)&W[(c0 + m) * DMODEL + kb + kg];
            Ws[kg+0][m] = wv.x; Ws[kg+1][m] = wv.y; Ws[kg+2][m] = wv.z; Ws[kg+3][m] = wv.w;
        }
        __syncthreads();
        #pragma unroll
        for (int kk = 0; kk < 32; ++kk){
            float4 av = *(const float4*)&Xs[kk][ty << 2];
            float4 bv = *(const float4*)&Ws[kk][tx << 2];
            float a[4] = {av.x, av.y, av.z, av.w};
            float b[4] = {bv.x, bv.y, bv.z, bv.w};
            #pragma unroll
            for (int ii = 0; ii < 4; ++ii)
                #pragma unroll
                for (int jj = 0; jj < 4; ++jj)
                    acc[ii][jj] = fmaf(a[ii], b[jj], acc[ii][jj]);
        }
    }
    #pragma unroll
    for (int ii = 0; ii < 4; ++ii){
        int r = r0 + (ty << 2) + ii;
        float4 o;
        o.x = acc[ii][0] + bias[c0 + (tx << 2) + 0];
        o.y = acc[ii][1] + bias[c0 + (tx << 2) + 1];
        o.z = acc[ii][2] + bias[c0 + (tx << 2) + 2];
        o.w = acc[ii][3] + bias[c0 + (tx << 2) + 3];
        *(float4*)&out[(size_t)r * DMODEL + c0 + (tx << 2)] = o;
    }
}

// ------- score GEMM slab via MFMA from pre-converted fp16 Q/K ---------------------
__global__ __launch_bounds__(256) void score_gemm(
    const __half* __restrict__ qH, const __half* __restrict__ kH,
    __half* __restrict__ Sh, const int bh0)
{
    const int bh = bh0 + blockIdx.z;
    const int r0 = blockIdx.x * 64, c0 = blockIdx.y * 64;
    __shared__ _Float16 Qs[64][72];      // +8 halves pad; row stride 144B
    __shared__ _Float16 Ks[64][72];
    const int tid = threadIdx.x;
    const int lane = tid & 63, wv = tid >> 6;
    const size_t qb = ((size_t)bh * LSEQ + r0) * DK;
    const size_t kb = ((size_t)bh * LSEQ + c0) * DK;
    #pragma unroll
    for (int i = 0; i < 2; ++i){
        int c = i * 256 + tid;
        int m = c >> 3, off8 = (c & 7) << 3;
        *(v8h*)&Qs[m][off8] = *(const v8h*)&qH[qb + (size_t)m * DK + off8];
        *(v8h*)&Ks[m][off8] = *(const v8h*)&kH[kb + (size_t)m * DK + off8];
    }
    __syncthreads();
    const int m0 = wv << 4;
    const int row = lane & 15, kq = lane >> 4;
    v8h a0 = *(const v8h*)&Qs[m0 + row][kq * 8];
    v8h a1 = *(const v8h*)&Qs[m0 + row][kq * 8 + 32];
    #pragma unroll
    for (int j0 = 0; j0 < 64; j0 += 16){
        v8h b0 = *(const v8h*)&Ks[j0 + row][kq * 8];
        v8h b1 = *(const v8h*)&Ks[j0 + row][kq * 8 + 32];
        v4f acc = {0.f, 0.f, 0.f, 0.f};
        acc = __builtin_amdgcn_mfma_f32_16x16x32_f16(a0, b0, acc, 0, 0, 0);
        acc = __builtin_amdgcn_mfma_f32_16x16x32_f16(a1, b1, acc, 0, 0, 0);
        #pragma unroll
        for (int r = 0; r < 4; ++r){
            int gr = r0 + m0 + kq * 4 + r;
            int gc = c0 + j0 + row;
            Sh[((size_t)blockIdx.z * LSEQ + gr) * LSEQ + gc] = (__half)acc[r];
        }
    }
}

// ---- shared tail: candidates -> exact f64 recheck -> exact top-38 -> softmax/AV --
__device__ __forceinline__ void finish_common(
    const int ncand, const int gl, const int bh, const int lane,
    const double qd, const double* __restrict__ kRow, const float* __restrict__ vB,
    float* __restrict__ ctx, int* __restrict__ jlsR, float* __restrict__ wlsR,
    double* __restrict__ sLds)
{
    const unsigned long long mlt = (1ull << lane) - 1ull;
    if (lane >= ncand) jlsR[lane] = 0;
    if (lane < 4) jlsR[64 + lane] = 0;
    int myJ = jlsR[lane];

    // exact f64 recheck: 8 lanes per candidate, 8 candidates per pass
    double q8[8];
    #pragma unroll
    for (int k = 0; k < 8; ++k) q8[k] = __shfl(qd, (lane & 7) + (k << 3));
    const int grp = lane >> 3, dl = lane & 7;
    const size_t kb = (size_t)bh * LSEQ;
    for (int e0 = 0; e0 < ncand; e0 += 8){
        int j = jlsR[e0 + grp];
        const double* __restrict__ kr = &kRow[(kb + j) * DK + dl];
        double s = 0.0;
        #pragma unroll
        for (int k = 0; k < 8; ++k) s = fma(q8[k], kr[k << 3], s);
        s += __shfl_xor(s, 1); s += __shfl_xor(s, 2); s += __shfl_xor(s, 4);
        if (dl == 0) sLds[e0 + grp] = s;
    }
    double myS = (lane < ncand) ? sLds[lane] : -1.0e308;

    // exact top-38 among candidates
    unsigned long long cu = (lane < ncand) ? mapu64(myS) : 0ull;
    unsigned long long T64 = 0ull;
    for (int bit = 63; bit >= 0; --bit){
        unsigned long long Tp = T64 | (1ull << bit);
        int c = __popcll(__ballot(cu >= Tp));
        if (c >= UK){ T64 = Tp; if (c == UK) break; }
    }
    const bool sel = (cu >= T64);              // ties kept, matching reference mask

    double xm = sel ? myS : -1.0e308;
    #pragma unroll
    for (int off = 32; off; off >>= 1) xm = fmax(xm, __shfl_xor(xm, off));
    float w = sel ? expf((float)(myS - xm)) : 0.0f;
    float z = w;
    #pragma unroll
    for (int off = 32; off; off >>= 1) z += __shfl_xor(z, off);
    unsigned long long bm = __ballot(sel);
    int p = __popcll(bm & mlt);
    if (sel){ wlsR[p] = w; jlsR[p] = myJ; }
    const int cnt = __popcll(bm);
    const float invZ = 1.0f / z;

    if (lane >= cnt) wlsR[lane] = 0.0f;
    if (lane < 4){ wlsR[64 + lane] = 0.0f; jlsR[64 + lane] = 0; }

    const float* __restrict__ vsl = vB + (size_t)bh * (LSEQ * DK);
    float o = 0.0f;
    for (int e = 0; e < cnt; e += 4){
        float w0 = wlsR[e],   w1 = wlsR[e+1], w2 = wlsR[e+2], w3 = wlsR[e+3];
        int   j0 = jlsR[e],   j1 = jlsR[e+1], j2 = jlsR[e+2], j3 = jlsR[e+3];
        float v0 = vsl[(size_t)j0 * DK + lane];
        float v1 = vsl[(size_t)j1 * DK + lane];
        float v2 = vsl[(size_t)j2 * DK + lane];
        float v3 = vsl[(size_t)j3 * DK + lane];
        o = fmaf(w0, v0, o); o = fmaf(w1, v1, o);
        o = fmaf(w2, v2, o); o = fmaf(w3, v3, o);
    }
    ctx[((size_t)(bh >> 3) * LSEQ + gl) * DMODEL + (bh & 7) * DK + lane] = o * invZ;
}

// ---- fallback-path row tail (f32 keys) -------------------------------------------
__device__ __forceinline__ void finish_row_f32(
    float (&acc)[32], const int gl, const int bh, const int lane, const float margin,
    const double qd, const double* __restrict__ kRow, const float* __restrict__ vB,
    float* __restrict__ ctx, int* __restrict__ jlsR, float* __restrict__ wlsR,
    double* __restrict__ sLds)
{
    unsigned u[32];
    #pragma unroll
    for (int ch = 0; ch < 32; ++ch) u[ch] = map32(acc[ch]);
    unsigned T = 0u; int curc = 2048;
    for (int bit = 31; bit >= 0; --bit){
        unsigned Tp = T | (1u << bit);
        int c = 0;
        #pragma unroll
        for (int ch = 0; ch < 32; ++ch) c += __popcll(__ballot(u[ch] >= Tp));
        if (c >= UK){ T = Tp; curc = c; }
        if (curc <= 48) break;
    }
    const unsigned Tlo = map32(unmap32(T) - margin);
    const unsigned long long mlt = (1ull << lane) - 1ull;
    int base = 0;
    #pragma unroll
    for (int ch = 0; ch < 32; ++ch){
        bool sel = (u[ch] >= Tlo);
        unsigned long long bm = __ballot(sel);
        int p = base + __popcll(bm & mlt);
        if (sel && p < 64) jlsR[p] = (ch << 6) + lane;
        base += __popcll(bm);
    }
    const int ncand = base > 64 ? 64 : base;
    finish_common(ncand, gl, bh, lane, qd, kRow, vB, ctx, jlsR, wlsR, sLds);
}

// ---------------- selection from fp16 S slab: u16 keys, one wave per row ----------
__global__ __launch_bounds__(256) void select_kernel(
    const __half* __restrict__ Sh, const double* __restrict__ qD,
    const double* __restrict__ kRow, const float* __restrict__ vB,
    float* __restrict__ ctx, const int bh0)
{
    __shared__ int    jls[4][68];
    __shared__ float  wls[4][68];
    __shared__ double sds[4][64];
    const int tid = threadIdx.x, lane = tid & 63, wv = tid >> 6;
    const int rgS = blockIdx.x * 4 + wv;
    const int bh = bh0 + (rgS >> 11), l = rgS & 2047;
    const double qd = qD[((size_t)bh * LSEQ + l) * DK + lane];
    unsigned u[32];                      // u16 monotone keys of the 32 owned scores
    const unsigned short* __restrict__ Srow =
        (const unsigned short*)Sh + (size_t)rgS * LSEQ;
    #pragma unroll
    for (int it = 0; it < 4; ++it){
        uint4 v = *(const uint4*)&Srow[it * 512 + (lane << 3)];
        unsigned ws[4] = {v.x, v.y, v.z, v.w};
        #pragma unroll
        for (int q = 0; q < 4; ++q){
            u[it*8 + 2*q]     = map16(ws[q] & 0xFFFFu);
            u[it*8 + 2*q + 1] = map16(ws[q] >> 16);
        }
    }
    // 16-bit bitsearch: T = exact 38th-largest fp16 key
    unsigned T = 0u; int curc = 2048;
    for (int bit = 15; bit >= 0; --bit){
        unsigned Tp = T | (1u << bit);
        int c = 0;
        #pragma unroll
        for (int ch = 0; ch < 32; ++ch) c += __popcll(__ballot(u[ch] >= Tp));
        if (c >= UK){ T = Tp; curc = c; }
        if (curc <= 48) break;
    }
    // threshold minus margin, conservatively rounded down -> superset candidates
    unsigned hb = (T & 0x8000u) ? (T & 0x7FFFu) : ((~T) & 0xFFFFu);
    float tf = __half2float(__ushort_as_half((unsigned short)hb)) - 2.2e-2f;
    unsigned short tlb = __half_as_ushort(__float2half_rd(tf));
    const unsigned Tlo = map16(tlb);

    const unsigned long long mlt = (1ull << lane) - 1ull;
    int base = 0;
    #pragma unroll
    for (int ch = 0; ch < 32; ++ch){
        bool sel = (u[ch] >= Tlo);
        unsigned long long bm = __ballot(sel);
        int p = base + __popcll(bm & mlt);
        int j = ((ch >> 3) << 9) + (lane << 3) + (ch & 7);
        if (sel && p < 64) jls[wv][p] = j;
        base += __popcll(bm);
    }
    const int ncand = base > 64 ? 64 : base;
    finish_common(ncand, l, bh, lane, qd, kRow, vB, ctx,
                  &jls[wv][0], &wls[wv][0], &sds[wv][0]);
}

// ---------------- fallback fused attention (R3/R4, proven) ------------------------
__global__ __launch_bounds__(256) void attn_kernel(
    const double* __restrict__ qD, const double* __restrict__ kRow,
    const float* __restrict__ vB, float* __restrict__ ctx)
{
    __shared__ float2 Kld2[16 * 66];
    __shared__ float  qsf[8][64];
    __shared__ int    jls[8][68];
    __shared__ float  wlsf[8][68];
    __shared__ double sds[8][64];

    const int tid = threadIdx.x, lane = tid & 63, wv = tid >> 6;
    const int bh = blockIdx.x >> 8;
    const int l0 = (blockIdx.x & 255) << 3;
    const int rA = l0 + (wv << 1), rB = rA + 1;

    for (int e = tid; e < 512; e += 256){
        int r = e >> 6, d = e & 63;
        qsf[r][d] = (float)qD[((size_t)bh * LSEQ + l0 + r) * DK + d];
    }
    const double qdA = qD[((size_t)bh * LSEQ + rA) * DK + lane];
    const double qdB = qD[((size_t)bh * LSEQ + rB) * DK + lane];

    float accA[32] = {}, accB[32] = {};
    const size_t kBase = (size_t)bh * (LSEQ * DK);

    for (int dh = 0; dh < 2; ++dh){
        __syncthreads();
        float qa[32], qb[32];
        #pragma unroll
        for (int i = 0; i < 8; ++i){
            float4 va = *(const float4*)&qsf[wv << 1][dh * 32 + i * 4];
            qa[i*4+0]=va.x; qa[i*4+1]=va.y; qa[i*4+2]=va.z; qa[i*4+3]=va.w;
            float4 vb4 = *(const float4*)&qsf[(wv << 1) + 1][dh * 32 + i * 4];
            qb[i*4+0]=vb4.x; qb[i*4+1]=vb4.y; qb[i*4+2]=vb4.z; qb[i*4+3]=vb4.w;
        }
        #pragma unroll
        for (int ch = 0; ch < 32; ++ch){
            const int cb = ch << 6;
            __syncthreads();
            #pragma unroll
            for (int i = 0; i < 4; ++i){
                int j   = i * 16 + (wv << 2) + (lane >> 4);
                int dpl = lane & 15;
                double2 kd = *(const double2*)&kRow[kBase + (size_t)(cb + j) * DK + dh * 32 + dpl * 2];
                Kld2[dpl * 66 + j] = make_float2((float)kd.x, (float)kd.y);
            }
            __syncthreads();
            float a0 = accA[ch], b0 = accB[ch];
            #pragma unroll
            for (int dpl = 0; dpl < 16; ++dpl){
                float2 k = Kld2[dpl * 66 + lane];
                a0 = fmaf(qa[2*dpl],   k.x, a0);
                a0 = fmaf(qa[2*dpl+1], k.y, a0);
                b0 = fmaf(qb[2*dpl],   k.x, b0);
                b0 = fmaf(qb[2*dpl+1], k.y, b0);
            }
            accA[ch] = a0; accB[ch] = b0;
        }
    }

    finish_row_f32(accA, rA, bh, lane, 1e-3f, qdA, kRow, vB, ctx,
                   &jls[wv<<1][0], &wlsf[wv<<1][0], &sds[wv<<1][0]);
    finish_row_f32(accB, rB, bh, lane, 1e-3f, qdB, kRow, vB, ctx,
                   &jls[(wv<<1)+1][0], &wlsf[(wv<<1)+1][0], &sds[(wv<<1)+1][0]);
}

extern "C" void kernel_launch(void* const* d_in, const int* in_sizes, int n_in,
                              void* d_out, int out_size, void* d_ws, size_t ws_size,
                              hipStream_t stream)
{
    const float* x  = (const float*)d_in[0];
    const float* Wq = (const float*)d_in[1];
    const float* bq = (const float*)d_in[2];
    const float* Wk = (const float*)d_in[3];
    const float* bk = (const float*)d_in[4];
    const float* Wv = (const float*)d_in[5];
    const float* bv = (const float*)d_in[6];
    const float* Wo = (const float*)d_in[7];
    const float* bo = (const float*)d_in[8];
    float* out = (float*)d_out;
    char* ws = (char*)d_ws;
    const size_t MiB = 1024 * 1024;
    // fixed: qD 16 | kRow 16 | vB 8 | ctx 8 | qH 4 | kH 4  (56 MiB); Sh slab after
    double* qD   = (double*)(ws);
    double* kRow = (double*)(ws + 16 * MiB);
    float*  vB   = (float*) (ws + 32 * MiB);
    float*  ctx  = (float*) (ws + 40 * MiB);
    __half* qH   = (__half*)(ws + 48 * MiB);
    __half* kH   = (__half*)(ws + 52 * MiB);
    __half* Sh   = (__half*)(ws + 56 * MiB);
    size_t avail = (ws_size > 56 * MiB) ? (ws_size - 56 * MiB) : 0;
    int slab = (int)(avail / (8 * MiB)); if (slab > 16) slab = 16;

    dim3 blk(256);
    gemm_qkv<<<dim3(64, 8, 3), blk, 0, stream>>>(x, Wq, Wk, Wv, bq, bk, bv,
                                                 qD, kRow, qH, kH, vB);
    if (slab >= 1){
        for (int s0 = 0; s0 < NHEAD * 2; s0 += slab){
            int nb = NHEAD * 2 - s0; if (nb > slab) nb = slab;
            score_gemm   <<<dim3(32, 32, nb), blk, 0, stream>>>(qH, kH, Sh, s0);
            select_kernel<<<dim3(nb * 512),   blk, 0, stream>>>(Sh, qD, kRow, vB, ctx, s0);
        }
    } else {
        attn_kernel<<<dim3(4096), blk, 0, stream>>>(qD, kRow, vB, ctx);
    }
    gemm_f32<<<dim3(64, 8), blk, 0, stream>>>(ctx, Wo, bo, out);
}

// Round 16
// 366.006 us; speedup vs baseline: 1.1957x; 1.1957x over previous
//
#include <hip/hip_runtime.h>
#include <hip/hip_fp16.h>
#include <math.h>

#define LSEQ   2048
#define DMODEL 512
#define NHEAD  8
#define DK     64
#define UK     38            // u = int(5*ln(2048)) = 38

typedef __attribute__((ext_vector_type(8))) _Float16 v8h;
typedef __attribute__((ext_vector_type(4))) float    v4f;

// order-preserving monotone maps (verified R2/R3)
__device__ __forceinline__ unsigned long long mapu64(double x){
    unsigned long long s = (unsigned long long)__double_as_longlong(x);
    return (s & 0x8000000000000000ull) ? ~s : (s | 0x8000000000000000ull);
}
__device__ __forceinline__ unsigned map32(float x){
    unsigned s = __float_as_uint(x);
    return (s & 0x80000000u) ? ~s : (s | 0x80000000u);
}
__device__ __forceinline__ float unmap32(unsigned u){
    unsigned s = (u & 0x80000000u) ? (u & 0x7fffffffu) : ~u;
    return __uint_as_float(s);
}
// u16 monotone map for raw half bits
__device__ __forceinline__ unsigned map16(unsigned h){
    return (h & 0x8000u) ? ((~h) & 0xFFFFu) : (h | 0x8000u);
}

// ------- fused Q/K (f64, exact) + V (f32) projections -----------------------------
// R14 configuration: measured-best (161us, VGPR 52, occupancy 38%). R15's
// register-staged dbuf ballooned VGPR to 164 -> occupancy 11% -> 231us. Reverted.
__global__ __launch_bounds__(256) void gemm_qkv(
    const float* __restrict__ X, const float* __restrict__ Wq,
    const float* __restrict__ Wk, const float* __restrict__ Wv,
    const float* __restrict__ bq, const float* __restrict__ bk,
    const float* __restrict__ bv,
    double* __restrict__ qD, double* __restrict__ kRow,
    __half* __restrict__ qH, __half* __restrict__ kH, float* __restrict__ vB)
{
    const int mode = blockIdx.z;                 // 0 = Q, 1 = K, 2 = V
    const float* __restrict__ W    = (mode == 0) ? Wq : (mode == 1 ? Wk : Wv);
    const float* __restrict__ bias = (mode == 0) ? bq : (mode == 1 ? bk : bv);
    const int r0 = blockIdx.x * 64, c0 = blockIdx.y * 64;
    __shared__ float Xs[32][68];
    __shared__ float Ws[32][68];
    const int tid = threadIdx.x;
    const int tx = tid & 15, ty = tid >> 4;

    if (mode < 2){
        double acc[4][4] = {};
        for (int kb = 0; kb < DMODEL; kb += 32){
            __syncthreads();
            #pragma unroll
            for (int i = 0; i < 2; ++i){
                int f4 = i * 256 + tid;
                int m = f4 >> 3, kg = (f4 & 7) << 2;
                float4 xv = *(const float4*)&X[(r0 + m) * DMODEL + kb + kg];
                Xs[kg+0][m] = xv.x; Xs[kg+1][m] = xv.y; Xs[kg+2][m] = xv.z; Xs[kg+3][m] = xv.w;
                float4 wv = *(const float4*)&W[(c0 + m) * DMODEL + kb + kg];
                Ws[kg+0][m] = wv.x; Ws[kg+1][m] = wv.y; Ws[kg+2][m] = wv.z; Ws[kg+3][m] = wv.w;
            }
            __syncthreads();
            #pragma unroll
            for (int kk = 0; kk < 32; ++kk){
                float4 av = *(const float4*)&Xs[kk][ty << 2];
                float4 bvv = *(const float4*)&Ws[kk][tx << 2];
                double a[4] = {(double)av.x, (double)av.y, (double)av.z, (double)av.w};
                double b[4] = {(double)bvv.x, (double)bvv.y, (double)bvv.z, (double)bvv.w};
                #pragma unroll
                for (int ii = 0; ii < 4; ++ii)
                    #pragma unroll
                    for (int jj = 0; jj < 4; ++jj)
                        acc[ii][jj] = fma(a[ii], b[jj], acc[ii][jj]);
            }
        }
        #pragma unroll
        for (int ii = 0; ii < 4; ++ii){
            int r = r0 + (ty << 2) + ii;
            int bidx = r >> 11, l = r & 2047;
            int h = c0 >> 6;
            size_t rowb = (size_t)(bidx * NHEAD + h) * LSEQ + l;
            _Float16 hv[4];
            #pragma unroll
            for (int jj = 0; jj < 4; ++jj){
                int dk = (tx << 2) + jj;
                double v = acc[ii][jj] + (double)bias[c0 + dk];
                if (mode == 0){
                    v *= 0.125;                  // exact pow2 scale
                    qD[rowb * DK + dk] = v;
                } else {
                    kRow[rowb * DK + dk] = v;
                }
                hv[jj] = (_Float16)v;
            }
            if (mode == 0) *(ushort4*)&qH[rowb * DK + (tx << 2)] = *(ushort4*)hv;
            else           *(ushort4*)&kH[rowb * DK + (tx << 2)] = *(ushort4*)hv;
        }
    } else {
        float acc[4][4] = {};
        for (int kb = 0; kb < DMODEL; kb += 32){
            __syncthreads();
            #pragma unroll
            for (int i = 0; i < 2; ++i){
                int f4 = i * 256 + tid;
                int m = f4 >> 3, kg = (f4 & 7) << 2;
                float4 xv = *(const float4*)&X[(r0 + m) * DMODEL + kb + kg];
                Xs[kg+0][m] = xv.x; Xs[kg+1][m] = xv.y; Xs[kg+2][m] = xv.z; Xs[kg+3][m] = xv.w;
                float4 wv = *(const float4*)&W[(c0 + m) * DMODEL + kb + kg];
                Ws[kg+0][m] = wv.x; Ws[kg+1][m] = wv.y; Ws[kg+2][m] = wv.z; Ws[kg+3][m] = wv.w;
            }
            __syncthreads();
            #pragma unroll
            for (int kk = 0; kk < 32; ++kk){
                float4 av = *(const float4*)&Xs[kk][ty << 2];
                float4 bvv = *(const float4*)&Ws[kk][tx << 2];
                float a[4] = {av.x, av.y, av.z, av.w};
                float b[4] = {bvv.x, bvv.y, bvv.z, bvv.w};
                #pragma unroll
                for (int ii = 0; ii < 4; ++ii)
                    #pragma unroll
                    for (int jj = 0; jj < 4; ++jj)
                        acc[ii][jj] = fmaf(a[ii], b[jj], acc[ii][jj]);
            }
        }
        #pragma unroll
        for (int ii = 0; ii < 4; ++ii){
            int r = r0 + (ty << 2) + ii;
            float4 o;
            o.x = acc[ii][0] + bias[c0 + (tx << 2) + 0];
            o.y = acc[ii][1] + bias[c0 + (tx << 2) + 1];
            o.z = acc[ii][2] + bias[c0 + (tx << 2) + 2];
            o.w = acc[ii][3] + bias[c0 + (tx << 2) + 3];
            int bidx = r >> 11, l = r & 2047, h = c0 >> 6;
            *(float4*)&vB[((size_t)(bidx * NHEAD + h) * LSEQ + l) * DK + (tx << 2)] = o;
        }
    }
}

// ---------------- f32 GEMM: O projection ------------------------------------------
__global__ __launch_bounds__(256) void gemm_f32(
    const float* __restrict__ X, const float* __restrict__ W,
    const float* __restrict__ bias, float* __restrict__ out)
{
    const int r0 = blockIdx.x * 64, c0 = blockIdx.y * 64;
    __shared__ float Xs[32][68];
    __shared__ float Ws[32][68];
    const int tid = threadIdx.x;
    const int tx = tid & 15, ty = tid >> 4;
    float acc[4][4] = {};
    for (int kb = 0; kb < DMODEL; kb += 32){
        __syncthreads();
        #pragma unroll
        for (int i = 0; i < 2; ++i){
            int f4 = i * 256 + tid;
            int m = f4 >> 3, kg = (f4 & 7) << 2;
            float4 xv = *(const float4*)&X[(r0 + m) * DMODEL + kb + kg];
            Xs[kg+0][m] = xv.x; Xs[kg+1][m] = xv.y; Xs[kg+2][m] = xv.z; Xs[kg+3][m] = xv.w;
            float4 wv = *(const float4*)&W[(c0 + m) * DMODEL + kb + kg];
            Ws[kg+0][m] = wv.x; Ws[kg+1][m] = wv.y; Ws[kg+2][m] = wv.z; Ws[kg+3][m] = wv.w;
        }
        __syncthreads();
        #pragma unroll
        for (int kk = 0; kk < 32; ++kk){
            float4 av = *(const float4*)&Xs[kk][ty << 2];
            float4 bv = *(const float4*)&Ws[kk][tx << 2];
            float a[4] = {av.x, av.y, av.z, av.w};
            float b[4] = {bv.x, bv.y, bv.z, bv.w};
            #pragma unroll
            for (int ii = 0; ii < 4; ++ii)
                #pragma unroll
                for (int jj = 0; jj < 4; ++jj)
                    acc[ii][jj] = fmaf(a[ii], b[jj], acc[ii][jj]);
        }
    }
    #pragma unroll
    for (int ii = 0; ii < 4; ++ii){
        int r = r0 + (ty << 2) + ii;
        float4 o;
        o.x = acc[ii][0] + bias[c0 + (tx << 2) + 0];
        o.y = acc[ii][1] + bias[c0 + (tx << 2) + 1];
        o.z = acc[ii][2] + bias[c0 + (tx << 2) + 2];
        o.w = acc[ii][3] + bias[c0 + (tx << 2) + 3];
        *(float4*)&out[(size_t)r * DMODEL + c0 + (tx << 2)] = o;
    }
}

// ------- score GEMM slab via MFMA from pre-converted fp16 Q/K ---------------------
__global__ __launch_bounds__(256) void score_gemm(
    const __half* __restrict__ qH, const __half* __restrict__ kH,
    __half* __restrict__ Sh, const int bh0)
{
    const int bh = bh0 + blockIdx.z;
    const int r0 = blockIdx.x * 64, c0 = blockIdx.y * 64;
    __shared__ _Float16 Qs[64][72];      // +8 halves pad; row stride 144B
    __shared__ _Float16 Ks[64][72];
    const int tid = threadIdx.x;
    const int lane = tid & 63, wv = tid >> 6;
    const size_t qb = ((size_t)bh * LSEQ + r0) * DK;
    const size_t kb = ((size_t)bh * LSEQ + c0) * DK;
    #pragma unroll
    for (int i = 0; i < 2; ++i){
        int c = i * 256 + tid;
        int m = c >> 3, off8 = (c & 7) << 3;
        *(v8h*)&Qs[m][off8] = *(const v8h*)&qH[qb + (size_t)m * DK + off8];
        *(v8h*)&Ks[m][off8] = *(const v8h*)&kH[kb + (size_t)m * DK + off8];
    }
    __syncthreads();
    const int m0 = wv << 4;
    const int row = lane & 15, kq = lane >> 4;
    v8h a0 = *(const v8h*)&Qs[m0 + row][kq * 8];
    v8h a1 = *(const v8h*)&Qs[m0 + row][kq * 8 + 32];
    #pragma unroll
    for (int j0 = 0; j0 < 64; j0 += 16){
        v8h b0 = *(const v8h*)&Ks[j0 + row][kq * 8];
        v8h b1 = *(const v8h*)&Ks[j0 + row][kq * 8 + 32];
        v4f acc = {0.f, 0.f, 0.f, 0.f};
        acc = __builtin_amdgcn_mfma_f32_16x16x32_f16(a0, b0, acc, 0, 0, 0);
        acc = __builtin_amdgcn_mfma_f32_16x16x32_f16(a1, b1, acc, 0, 0, 0);
        #pragma unroll
        for (int r = 0; r < 4; ++r){
            int gr = r0 + m0 + kq * 4 + r;
            int gc = c0 + j0 + row;
            Sh[((size_t)blockIdx.z * LSEQ + gr) * LSEQ + gc] = (__half)acc[r];
        }
    }
}

// ---- shared tail: candidates -> exact f64 recheck -> exact top-38 -> softmax/AV --
__device__ __forceinline__ void finish_common(
    const int ncand, const int gl, const int bh, const int lane,
    const double qd, const double* __restrict__ kRow, const float* __restrict__ vB,
    float* __restrict__ ctx, int* __restrict__ jlsR, float* __restrict__ wlsR,
    double* __restrict__ sLds)
{
    const unsigned long long mlt = (1ull << lane) - 1ull;
    if (lane >= ncand) jlsR[lane] = 0;
    if (lane < 4) jlsR[64 + lane] = 0;
    int myJ = jlsR[lane];

    // exact f64 recheck: 8 lanes per candidate, 8 candidates per pass
    double q8[8];
    #pragma unroll
    for (int k = 0; k < 8; ++k) q8[k] = __shfl(qd, (lane & 7) + (k << 3));
    const int grp = lane >> 3, dl = lane & 7;
    const size_t kb = (size_t)bh * LSEQ;
    for (int e0 = 0; e0 < ncand; e0 += 8){
        int j = jlsR[e0 + grp];
        const double* __restrict__ kr = &kRow[(kb + j) * DK + dl];
        double s = 0.0;
        #pragma unroll
        for (int k = 0; k < 8; ++k) s = fma(q8[k], kr[k << 3], s);
        s += __shfl_xor(s, 1); s += __shfl_xor(s, 2); s += __shfl_xor(s, 4);
        if (dl == 0) sLds[e0 + grp] = s;
    }
    double myS = (lane < ncand) ? sLds[lane] : -1.0e308;

    // exact top-38 among candidates
    unsigned long long cu = (lane < ncand) ? mapu64(myS) : 0ull;
    unsigned long long T64 = 0ull;
    for (int bit = 63; bit >= 0; --bit){
        unsigned long long Tp = T64 | (1ull << bit);
        int c = __popcll(__ballot(cu >= Tp));
        if (c >= UK){ T64 = Tp; if (c == UK) break; }
    }
    const bool sel = (cu >= T64);              // ties kept, matching reference mask

    double xm = sel ? myS : -1.0e308;
    #pragma unroll
    for (int off = 32; off; off >>= 1) xm = fmax(xm, __shfl_xor(xm, off));
    float w = sel ? expf((float)(myS - xm)) : 0.0f;
    float z = w;
    #pragma unroll
    for (int off = 32; off; off >>= 1) z += __shfl_xor(z, off);
    unsigned long long bm = __ballot(sel);
    int p = __popcll(bm & mlt);
    if (sel){ wlsR[p] = w; jlsR[p] = myJ; }
    const int cnt = __popcll(bm);
    const float invZ = 1.0f / z;

    if (lane >= cnt) wlsR[lane] = 0.0f;
    if (lane < 4){ wlsR[64 + lane] = 0.0f; jlsR[64 + lane] = 0; }

    const float* __restrict__ vsl = vB + (size_t)bh * (LSEQ * DK);
    float o = 0.0f;
    for (int e = 0; e < cnt; e += 4){
        float w0 = wlsR[e],   w1 = wlsR[e+1], w2 = wlsR[e+2], w3 = wlsR[e+3];
        int   j0 = jlsR[e],   j1 = jlsR[e+1], j2 = jlsR[e+2], j3 = jlsR[e+3];
        float v0 = vsl[(size_t)j0 * DK + lane];
        float v1 = vsl[(size_t)j1 * DK + lane];
        float v2 = vsl[(size_t)j2 * DK + lane];
        float v3 = vsl[(size_t)j3 * DK + lane];
        o = fmaf(w0, v0, o); o = fmaf(w1, v1, o);
        o = fmaf(w2, v2, o); o = fmaf(w3, v3, o);
    }
    ctx[((size_t)(bh >> 3) * LSEQ + gl) * DMODEL + (bh & 7) * DK + lane] = o * invZ;
}

// ---- fallback-path row tail (f32 keys) -------------------------------------------
__device__ __forceinline__ void finish_row_f32(
    float (&acc)[32], const int gl, const int bh, const int lane, const float margin,
    const double qd, const double* __restrict__ kRow, const float* __restrict__ vB,
    float* __restrict__ ctx, int* __restrict__ jlsR, float* __restrict__ wlsR,
    double* __restrict__ sLds)
{
    unsigned u[32];
    #pragma unroll
    for (int ch = 0; ch < 32; ++ch) u[ch] = map32(acc[ch]);
    unsigned T = 0u; int curc = 2048;
    for (int bit = 31; bit >= 0; --bit){
        unsigned Tp = T | (1u << bit);
        int c = 0;
        #pragma unroll
        for (int ch = 0; ch < 32; ++ch) c += __popcll(__ballot(u[ch] >= Tp));
        if (c >= UK){ T = Tp; curc = c; }
        if (curc <= 48) break;
    }
    const unsigned Tlo = map32(unmap32(T) - margin);
    const unsigned long long mlt = (1ull << lane) - 1ull;
    int base = 0;
    #pragma unroll
    for (int ch = 0; ch < 32; ++ch){
        bool sel = (u[ch] >= Tlo);
        unsigned long long bm = __ballot(sel);
        int p = base + __popcll(bm & mlt);
        if (sel && p < 64) jlsR[p] = (ch << 6) + lane;
        base += __popcll(bm);
    }
    const int ncand = base > 64 ? 64 : base;
    finish_common(ncand, gl, bh, lane, qd, kRow, vB, ctx, jlsR, wlsR, sLds);
}

// ---------------- selection from fp16 S slab: u16 keys, one wave per row ----------
__global__ __launch_bounds__(256) void select_kernel(
    const __half* __restrict__ Sh, const double* __restrict__ qD,
    const double* __restrict__ kRow, const float* __restrict__ vB,
    float* __restrict__ ctx, const int bh0)
{
    __shared__ int    jls[4][68];
    __shared__ float  wls[4][68];
    __shared__ double sds[4][64];
    const int tid = threadIdx.x, lane = tid & 63, wv = tid >> 6;
    const int rgS = blockIdx.x * 4 + wv;
    const int bh = bh0 + (rgS >> 11), l = rgS & 2047;
    const double qd = qD[((size_t)bh * LSEQ + l) * DK + lane];
    unsigned u[32];                      // u16 monotone keys of the 32 owned scores
    const unsigned short* __restrict__ Srow =
        (const unsigned short*)Sh + (size_t)rgS * LSEQ;
    #pragma unroll
    for (int it = 0; it < 4; ++it){
        uint4 v = *(const uint4*)&Srow[it * 512 + (lane << 3)];
        unsigned ws[4] = {v.x, v.y, v.z, v.w};
        #pragma unroll
        for (int q = 0; q < 4; ++q){
            u[it*8 + 2*q]     = map16(ws[q] & 0xFFFFu);
            u[it*8 + 2*q + 1] = map16(ws[q] >> 16);
        }
    }
    // 16-bit bitsearch: T = exact 38th-largest fp16 key
    unsigned T = 0u; int curc = 2048;
    for (int bit = 15; bit >= 0; --bit){
        unsigned Tp = T | (1u << bit);
        int c = 0;
        #pragma unroll
        for (int ch = 0; ch < 32; ++ch) c += __popcll(__ballot(u[ch] >= Tp));
        if (c >= UK){ T = Tp; curc = c; }
        if (curc <= 48) break;
    }
    // threshold minus margin, conservatively rounded down -> superset candidates
    unsigned hb = (T & 0x8000u) ? (T & 0x7FFFu) : ((~T) & 0xFFFFu);
    float tf = __half2float(__ushort_as_half((unsigned short)hb)) - 2.2e-2f;
    unsigned short tlb = __half_as_ushort(__float2half_rd(tf));
    const unsigned Tlo = map16(tlb);

    const unsigned long long mlt = (1ull << lane) - 1ull;
    int base = 0;
    #pragma unroll
    for (int ch = 0; ch < 32; ++ch){
        bool sel = (u[ch] >= Tlo);
        unsigned long long bm = __ballot(sel);
        int p = base + __popcll(bm & mlt);
        int j = ((ch >> 3) << 9) + (lane << 3) + (ch & 7);
        if (sel && p < 64) jls[wv][p] = j;
        base += __popcll(bm);
    }
    const int ncand = base > 64 ? 64 : base;
    finish_common(ncand, l, bh, lane, qd, kRow, vB, ctx,
                  &jls[wv][0], &wls[wv][0], &sds[wv][0]);
}

// ---------------- fallback fused attention (R3/R4, proven) ------------------------
__global__ __launch_bounds__(256) void attn_kernel(
    const double* __restrict__ qD, const double* __restrict__ kRow,
    const float* __restrict__ vB, float* __restrict__ ctx)
{
    __shared__ float2 Kld2[16 * 66];
    __shared__ float  qsf[8][64];
    __shared__ int    jls[8][68];
    __shared__ float  wlsf[8][68];
    __shared__ double sds[8][64];

    const int tid = threadIdx.x, lane = tid & 63, wv = tid >> 6;
    const int bh = blockIdx.x >> 8;
    const int l0 = (blockIdx.x & 255) << 3;
    const int rA = l0 + (wv << 1), rB = rA + 1;

    for (int e = tid; e < 512; e += 256){
        int r = e >> 6, d = e & 63;
        qsf[r][d] = (float)qD[((size_t)bh * LSEQ + l0 + r) * DK + d];
    }
    const double qdA = qD[((size_t)bh * LSEQ + rA) * DK + lane];
    const double qdB = qD[((size_t)bh * LSEQ + rB) * DK + lane];

    float accA[32] = {}, accB[32] = {};
    const size_t kBase = (size_t)bh * (LSEQ * DK);

    for (int dh = 0; dh < 2; ++dh){
        __syncthreads();
        float qa[32], qb[32];
        #pragma unroll
        for (int i = 0; i < 8; ++i){
            float4 va = *(const float4*)&qsf[wv << 1][dh * 32 + i * 4];
            qa[i*4+0]=va.x; qa[i*4+1]=va.y; qa[i*4+2]=va.z; qa[i*4+3]=va.w;
            float4 vb4 = *(const float4*)&qsf[(wv << 1) + 1][dh * 32 + i * 4];
            qb[i*4+0]=vb4.x; qb[i*4+1]=vb4.y; qb[i*4+2]=vb4.z; qb[i*4+3]=vb4.w;
        }
        #pragma unroll
        for (int ch = 0; ch < 32; ++ch){
            const int cb = ch << 6;
            __syncthreads();
            #pragma unroll
            for (int i = 0; i < 4; ++i){
                int j   = i * 16 + (wv << 2) + (lane >> 4);
                int dpl = lane & 15;
                double2 kd = *(const double2*)&kRow[kBase + (size_t)(cb + j) * DK + dh * 32 + dpl * 2];
                Kld2[dpl * 66 + j] = make_float2((float)kd.x, (float)kd.y);
            }
            __syncthreads();
            float a0 = accA[ch], b0 = accB[ch];
            #pragma unroll
            for (int dpl = 0; dpl < 16; ++dpl){
                float2 k = Kld2[dpl * 66 + lane];
                a0 = fmaf(qa[2*dpl],   k.x, a0);
                a0 = fmaf(qa[2*dpl+1], k.y, a0);
                b0 = fmaf(qb[2*dpl],   k.x, b0);
                b0 = fmaf(qb[2*dpl+1], k.y, b0);
            }
            accA[ch] = a0; accB[ch] = b0;
        }
    }

    finish_row_f32(accA, rA, bh, lane, 1e-3f, qdA, kRow, vB, ctx,
                   &jls[wv<<1][0], &wlsf[wv<<1][0], &sds[wv<<1][0]);
    finish_row_f32(accB, rB, bh, lane, 1e-3f, qdB, kRow, vB, ctx,
                   &jls[(wv<<1)+1][0], &wlsf[(wv<<1)+1][0], &sds[(wv<<1)+1][0]);
}

extern "C" void kernel_launch(void* const* d_in, const int* in_sizes, int n_in,
                              void* d_out, int out_size, void* d_ws, size_t ws_size,
                              hipStream_t stream)
{
    const float* x  = (const float*)d_in[0];
    const float* Wq = (const float*)d_in[1];
    const float* bq = (const float*)d_in[2];
    const float* Wk = (const float*)d_in[3];
    const float* bk = (const float*)d_in[4];
    const float* Wv = (const float*)d_in[5];
    const float* bv = (const float*)d_in[6];
    const float* Wo = (const float*)d_in[7];
    const float* bo = (const float*)d_in[8];
    float* out = (float*)d_out;
    char* ws = (char*)d_ws;
    const size_t MiB = 1024 * 1024;
    // fixed: qD 16 | kRow 16 | vB 8 | ctx 8 | qH 4 | kH 4  (56 MiB); Sh slab after
    double* qD   = (double*)(ws);
    double* kRow = (double*)(ws + 16 * MiB);
    float*  vB   = (float*) (ws + 32 * MiB);
    float*  ctx  = (float*) (ws + 40 * MiB);
    __half* qH   = (__half*)(ws + 48 * MiB);
    __half* kH   = (__half*)(ws + 52 * MiB);
    __half* Sh   = (__half*)(ws + 56 * MiB);
    size_t avail = (ws_size > 56 * MiB) ? (ws_size - 56 * MiB) : 0;
    int slab = (int)(avail / (8 * MiB)); if (slab > 16) slab = 16;

    dim3 blk(256);
    gemm_qkv<<<dim3(64, 8, 3), blk, 0, stream>>>(x, Wq, Wk, Wv, bq, bk, bv,
                                                 qD, kRow, qH, kH, vB);
    if (slab >= 1){
        for (int s0 = 0; s0 < NHEAD * 2; s0 += slab){
            int nb = NHEAD * 2 - s0; if (nb > slab) nb = slab;
            score_gemm   <<<dim3(32, 32, nb), blk, 0, stream>>>(qH, kH, Sh, s0);
            select_kernel<<<dim3(nb * 512),   blk, 0, stream>>>(Sh, qD, kRow, vB, ctx, s0);
        }
    } else {
        attn_kernel<<<dim3(4096), blk, 0, stream>>>(qD, kRow, vB, ctx);
    }
    gemm_f32<<<dim3(64, 8), blk, 0, stream>>>(ctx, Wo, bo, out);
}